// Round 17
// baseline (1191.531 us; speedup 1.0000x reference)
//
#include <hip/hip_runtime.h>
#include <hip/hip_bf16.h>

#define N_USERS 100000
#define N_ITEMS 50000
#define N_TOTAL 150000
#define NNZ     4000000
#define ALPHA_F 0.8f
#define ELL_CAP 128

#define X_SCAT 1024
#define X_COPY 128
#define X_TIMG 1024
#define X_TTXT 128
#define G_GEMM 3125           // N_ITEMS / 16 exactly
#define NC_IMG 32             // img chunks of K=128
#define NC_ALL 35             // + 3 txt chunks of K=128

typedef __attribute__((ext_vector_type(8))) short bf16x8;
typedef __attribute__((ext_vector_type(4))) float f32x4;

static __device__ __forceinline__ short f2bf(float f) {
    unsigned u = __builtin_bit_cast(unsigned, f);
    unsigned r = (u + 0x7fff + ((u >> 16) & 1)) >> 16;   // RTNE
    return (short)r;
}
static __device__ __forceinline__ unsigned pack_bf2(float a, float b) {
    return (unsigned)(unsigned short)f2bf(a) | ((unsigned)(unsigned short)f2bf(b) << 16);
}
static __device__ __forceinline__ float bf_lo(unsigned u) { return __uint_as_float(u << 16); }
static __device__ __forceinline__ float bf_hi(unsigned u) { return __uint_as_float(u & 0xFFFF0000u); }

static __device__ __forceinline__ void gload_lds16(const void* src, void* dst) {
    __builtin_amdgcn_global_load_lds(
        (const __attribute__((address_space(1))) unsigned*)src,
        (__attribute__((address_space(3))) unsigned*)dst, 16, 0, 0);
}

// ---------------------------------------------------------------- prep
// zero cnt + tiled/swizzled bf16 B (K=128 chunks, 16KB tiles):
// WtT[c][n][k'] byte = c*16384 + n*256 + ((k'*2) ^ ((n&7)<<4))

__global__ __launch_bounds__(256) void prep_kernel(const float* __restrict__ Wimg,
                                                   const float* __restrict__ Wtxt,
                                                   int* __restrict__ cnt,
                                                   char* __restrict__ WtiT,
                                                   char* __restrict__ WttT) {
    const int T0 = N_TOTAL;
    const int T1 = T0 + 4096 * 64;
    const int T2 = T1 + 384 * 64;
    int i = blockIdx.x * 256 + threadIdx.x;
    int stride = gridDim.x * 256;
    for (; i < T2; i += stride) {
        if (i < T0) {
            cnt[i] = 0;
        } else if (i < T1) {
            int idx = i - T0; int k = idx >> 6, n = idx & 63;
            int c = k >> 7, kk = k & 127;
            *(short*)(WtiT + c * 16384 + n * 256 + ((kk * 2) ^ ((n & 7) << 4)))
                = f2bf(Wimg[(size_t)k * 64 + n]);
        } else {
            int idx = i - T1; int k = idx >> 6, n = idx & 63;
            int c = k >> 7, kk = k & 127;
            *(short*)(WttT + c * 16384 + n * 256 + ((kk * 2) ^ ((n & 7) << 4)))
                = f2bf(Wtxt[(size_t)k * 64 + n]);
        }
    }
}

// ---------------------------------------------------------------- xpose kernel
// [0, X_SCAT):      ELL scatter
// [.., +X_COPY):    user pref -> bf16 mirror
// [.., +X_TIMG):    img A -> packed bf16 At (sequential read, L2-buffered write)
// [.., +X_TTXT):    txt A -> packed At chunks 32..34
// At[b][cc][rr][kk]: byte = (b*35+cc)*4096 + rr*256 + ((kk*2) ^ ((rr&7)<<4))

__global__ __launch_bounds__(256) void xpose_kernel(
        const float* __restrict__ Aimg, const float* __restrict__ Atxt,
        char* __restrict__ At,
        const int* __restrict__ rows, const int* __restrict__ cols,
        const float* __restrict__ vals, int* __restrict__ cnt, int2* __restrict__ ell,
        const float* __restrict__ img_pref, const float* __restrict__ txt_pref,
        unsigned* __restrict__ egob) {
    int b = blockIdx.x;
    int t = threadIdx.x;

    if (b < X_SCAT) {
        int i = b * 256 + t;
        int stride = X_SCAT * 256;
        for (; i < NNZ; i += stride) {
            int r = rows[i];
            int p = atomicAdd(&cnt[r], 1);
            if (p < ELL_CAP)
                ell[(size_t)r * ELL_CAP + p] = make_int2(cols[i], __float_as_int(vals[i]));
        }
        return;
    }
    if (b < X_SCAT + X_COPY) {
        int idx = (b - X_SCAT) * 256 + t;
        int stride = X_COPY * 256;
        for (; idx < N_USERS * 16; idx += stride) {
            int row = idx >> 4, w4 = (idx & 15) << 2;
            float4 iv = *reinterpret_cast<const float4*>(&img_pref[(size_t)row * 64 + w4]);
            float4 tv = *reinterpret_cast<const float4*>(&txt_pref[(size_t)row * 64 + w4]);
            uint4 m;
            m.x = pack_bf2(iv.x, tv.x); m.y = pack_bf2(iv.y, tv.y);
            m.z = pack_bf2(iv.z, tv.z); m.w = pack_bf2(iv.w, tv.w);
            *reinterpret_cast<uint4*>(&egob[(size_t)row * 64 + w4]) = m;
        }
        return;
    }
    if (b < X_SCAT + X_COPY + X_TIMG) {
        // ---- img transpose: read sequential float4, write packed bf16 ----
        const float4* A4 = reinterpret_cast<const float4*>(Aimg);
        const size_t NF4 = (size_t)N_ITEMS * 1024;
        const size_t S = (size_t)X_TIMG * 256;
        size_t g = (size_t)(b - X_SCAT - X_COPY) * 256 + t;
        auto wr = [&](size_t gi, float4 v) {
            unsigned f = (unsigned)(gi * 4);
            unsigned r = f >> 12, k = f & 4095;
            unsigned bb = r >> 4, rr = r & 15, cc = k >> 7, kk = k & 127;
            char* dst = At + ((size_t)bb * 35 + cc) * 4096 + rr * 256
                        + ((kk * 2) ^ ((rr & 7) << 4));
            uint2 u; u.x = pack_bf2(v.x, v.y); u.y = pack_bf2(v.z, v.w);
            *reinterpret_cast<uint2*>(dst) = u;
        };
        for (; g + 3 * S < NF4; g += 4 * S) {
            float4 v0 = A4[g], v1 = A4[g + S], v2 = A4[g + 2 * S], v3 = A4[g + 3 * S];
            wr(g, v0); wr(g + S, v1); wr(g + 2 * S, v2); wr(g + 3 * S, v3);
        }
        for (; g < NF4; g += S) wr(g, A4[g]);
        return;
    }
    {
        // ---- txt transpose -> chunks 32..34 ----
        const float4* A4 = reinterpret_cast<const float4*>(Atxt);
        const size_t NF4 = (size_t)N_ITEMS * 96;
        const size_t S = (size_t)X_TTXT * 256;
        size_t g = (size_t)(b - X_SCAT - X_COPY - X_TIMG) * 256 + t;
        auto wr = [&](size_t gi, float4 v) {
            unsigned f = (unsigned)(gi * 4);
            unsigned r = f / 384, k = f - r * 384;
            unsigned bb = r >> 4, rr = r & 15, cc = 32 + (k >> 7), kk = k & 127;
            char* dst = At + ((size_t)bb * 35 + cc) * 4096 + rr * 256
                        + ((kk * 2) ^ ((rr & 7) << 4));
            uint2 u; u.x = pack_bf2(v.x, v.y); u.y = pack_bf2(v.z, v.w);
            *reinterpret_cast<uint2*>(dst) = u;
        };
        for (; g + 3 * S < NF4; g += 4 * S) {
            float4 v0 = A4[g], v1 = A4[g + S], v2 = A4[g + 2 * S], v3 = A4[g + 3 * S];
            wr(g, v0); wr(g + S, v1); wr(g + 2 * S, v2); wr(g + 3 * S, v3);
        }
        for (; g < NF4; g += S) wr(g, A4[g]);
        return;
    }
}

// ---------------------------------------------------------------- GEMM (pass 2)
// 16 rows/block. Per chunk (K=128): stage A 4KB (1 linear gload/wave from At)
// + B 16KB (4 linear gloads/wave from WtT). comp = pure LDS + MFMA, bf16 direct
// (no f2bf). counted vmcnt(5) keeps next chunk's loads in flight across barriers.

__global__ __launch_bounds__(256, 4) void gemm_kernel(
        const char* __restrict__ At,
        const char* __restrict__ WtiT, const char* __restrict__ WttT,
        const float* __restrict__ bimg, const float* __restrict__ btxt,
        unsigned* __restrict__ egob_items) {
    __shared__ __align__(16) char abuf[2][4096];
    __shared__ __align__(16) char bbuf[2][16384];
    const int t = threadIdx.x;
    const int wave = t >> 6, lane = t & 63;
    const int col = lane & 15, kb = lane >> 4;
    const int blk = blockIdx.x;
    const int row0 = blk * 16;

    auto stage = [&](int ci, int bi) {
        gload_lds16(At + ((size_t)blk * 35 + ci) * 4096 + wave * 1024 + lane * 16,
                    abuf[bi] + wave * 1024 + lane * 16);
        const char* BT = (ci < NC_IMG) ? WtiT + (size_t)ci * 16384
                                       : WttT + (size_t)(ci - NC_IMG) * 16384;
        #pragma unroll
        for (int q = 0; q < 4; ++q) {
            int off = (q * 4 + wave) * 1024 + lane * 16;
            gload_lds16(BT + off, bbuf[bi] + off);
        }
    };

    // comp: 4 k-steps; A row = col, B col n = 16*wave+col; both pre-swizzled
    auto comp = [&](int bi, f32x4& acc) {
        const int r = col;
        const int aswz = (r & 7) << 4;
        const char* ab = abuf[bi] + r * 256;
        const int n = 16 * wave + col;
        const char* bb = bbuf[bi] + n * 256;
        const int bswz = (n & 7) << 4;
        #pragma unroll
        for (int ks = 0; ks < 4; ++ks) {
            int o = ks * 64 + kb * 16;
            bf16x8 af = *(const bf16x8*)(ab + (o ^ aswz));
            bf16x8 bf = *(const bf16x8*)(bb + (o ^ bswz));
            acc = __builtin_amdgcn_mfma_f32_16x16x32_bf16(af, bf, acc, 0, 0, 0);
        }
    };

    f32x4 ai = {0.f,0.f,0.f,0.f}, at4 = {0.f,0.f,0.f,0.f};

    stage(0, 0);
    for (int ci = 0; ci < NC_ALL; ++ci) {
        int bi = ci & 1;
        if (ci + 1 < NC_ALL) {
            stage(ci + 1, bi ^ 1);
            asm volatile("s_waitcnt vmcnt(5)" ::: "memory");   // stage(ci) done; next in flight
        } else {
            asm volatile("s_waitcnt vmcnt(0)" ::: "memory");
        }
        __builtin_amdgcn_s_barrier();
        __builtin_amdgcn_sched_barrier(0);
        if (ci < NC_IMG) comp(bi, ai);
        else             comp(bi, at4);
        __builtin_amdgcn_sched_barrier(0);
        __builtin_amdgcn_s_barrier();
    }

    // ---------------- bias + cross-wave L2 norm + mirror store ----------------
    float bv_i = bimg[16 * wave + col];
    float bv_t = btxt[16 * wave + col];
    float ssi[4], sst[4];
    #pragma unroll
    for (int i = 0; i < 4; ++i) {
        ai[i] += bv_i; at4[i] += bv_t;
        ssi[i] = ai[i] * ai[i];
        sst[i] = at4[i] * at4[i];
    }
    #pragma unroll
    for (int off = 1; off < 16; off <<= 1) {
        #pragma unroll
        for (int i = 0; i < 4; ++i) {
            ssi[i] += __shfl_xor(ssi[i], off, 64);
            sst[i] += __shfl_xor(sst[i], off, 64);
        }
    }
    float* S = (float*)abuf;           // [2][4 waves][16 rows]
    __syncthreads();
    if (col == 0) {
        #pragma unroll
        for (int i = 0; i < 4; ++i) {
            S[wave * 16 + kb * 4 + i]      = ssi[i];
            S[64 + wave * 16 + kb * 4 + i] = sst[i];
        }
    }
    __syncthreads();
    #pragma unroll
    for (int i = 0; i < 4; ++i) {
        int r = kb * 4 + i;
        float ti = S[r] + S[16 + r] + S[32 + r] + S[48 + r];     // fixed order
        float tt = S[64 + r] + S[80 + r] + S[96 + r] + S[112 + r];
        float rni = 1.0f / fmaxf(sqrtf(ti), 1e-12f);
        float rnt = 1.0f / fmaxf(sqrtf(tt), 1e-12f);
        egob_items[(size_t)(row0 + r) * 64 + 16 * wave + col] =
            pack_bf2(ai[i] * rni, at4[i] * rnt);
    }
}

// ---------------------------------------------------------------- SpMM layer 1 + fused sort

__global__ __launch_bounds__(256) void spmm_sort_kernel(
        const int* __restrict__ cnt, int2* __restrict__ ell,
        const unsigned* __restrict__ xb, unsigned* __restrict__ outb) {
    __shared__ __align__(16) int2 srt[4][ELL_CAP];
    int wid = threadIdx.x >> 6, lane = threadIdx.x & 63;
    int row = blockIdx.x * 4 + wid;
    bool valid = row < N_TOTAL;
    int deg = 0;
    int2* base = nullptr;
    int2 e0 = make_int2(0x7FFFFFFF, 0), e1 = e0;
    if (valid) {
        deg = min(cnt[row], ELL_CAP);
        base = ell + (size_t)row * ELL_CAP;
        if (lane < deg)      e0 = base[lane];
        if (lane + 64 < deg) e1 = base[lane + 64];
    }
    #pragma unroll
    for (int k = 2; k <= 128; k <<= 1) {
        #pragma unroll
        for (int j = 64; j >= 1; j >>= 1) {
            if (j >= k) continue;
            if (j == 64) {
                if (e0.x > e1.x) { int2 tmp = e0; e0 = e1; e1 = tmp; }
            } else {
                int2 p0, p1;
                p0.x = __shfl_xor(e0.x, j, 64); p0.y = __shfl_xor(e0.y, j, 64);
                p1.x = __shfl_xor(e1.x, j, 64); p1.y = __shfl_xor(e1.y, j, 64);
                bool up0 = ((lane & k) == 0);
                bool up1 = (((lane + 64) & k) == 0);
                bool lo0 = ((lane & j) == 0);
                bool keepmin0 = (up0 == lo0);
                bool keepmin1 = (up1 == lo0);
                if (keepmin0 ? (e0.x > p0.x) : (e0.x < p0.x)) e0 = p0;
                if (keepmin1 ? (e1.x > p1.x) : (e1.x < p1.x)) e1 = p1;
            }
        }
    }
    if (valid) {
        if (lane < deg)      base[lane]      = e0;
        if (lane + 64 < deg) base[lane + 64] = e1;
    }
    srt[wid][lane] = e0;
    srt[wid][lane + 64] = e1;
    __syncthreads();
    if (!valid) return;
    unsigned sw = xb[(size_t)row * 64 + lane];
    float2 acc;
    acc.x = ALPHA_F * bf_lo(sw);
    acc.y = ALPHA_F * bf_hi(sw);
    const int2* s = srt[wid];
    int i = 0;
    for (; i + 8 <= deg; i += 8) {
        int4 p0 = *reinterpret_cast<const int4*>(s + i);
        int4 p1 = *reinterpret_cast<const int4*>(s + i + 2);
        int4 p2 = *reinterpret_cast<const int4*>(s + i + 4);
        int4 p3 = *reinterpret_cast<const int4*>(s + i + 6);
        unsigned g0 = xb[(size_t)p0.x * 64 + lane];
        unsigned g1 = xb[(size_t)p0.z * 64 + lane];
        unsigned g2 = xb[(size_t)p1.x * 64 + lane];
        unsigned g3 = xb[(size_t)p1.z * 64 + lane];
        unsigned g4 = xb[(size_t)p2.x * 64 + lane];
        unsigned g5 = xb[(size_t)p2.z * 64 + lane];
        unsigned g6 = xb[(size_t)p3.x * 64 + lane];
        unsigned g7 = xb[(size_t)p3.z * 64 + lane];
        float v0 = __int_as_float(p0.y), v1 = __int_as_float(p0.w);
        float v2 = __int_as_float(p1.y), v3 = __int_as_float(p1.w);
        float v4 = __int_as_float(p2.y), v5 = __int_as_float(p2.w);
        float v6 = __int_as_float(p3.y), v7 = __int_as_float(p3.w);
        acc.x = fmaf(v0, bf_lo(g0), acc.x); acc.y = fmaf(v0, bf_hi(g0), acc.y);
        acc.x = fmaf(v1, bf_lo(g1), acc.x); acc.y = fmaf(v1, bf_hi(g1), acc.y);
        acc.x = fmaf(v2, bf_lo(g2), acc.x); acc.y = fmaf(v2, bf_hi(g2), acc.y);
        acc.x = fmaf(v3, bf_lo(g3), acc.x); acc.y = fmaf(v3, bf_hi(g3), acc.y);
        acc.x = fmaf(v4, bf_lo(g4), acc.x); acc.y = fmaf(v4, bf_hi(g4), acc.y);
        acc.x = fmaf(v5, bf_lo(g5), acc.x); acc.y = fmaf(v5, bf_hi(g5), acc.y);
        acc.x = fmaf(v6, bf_lo(g6), acc.x); acc.y = fmaf(v6, bf_hi(g6), acc.y);
        acc.x = fmaf(v7, bf_lo(g7), acc.x); acc.y = fmaf(v7, bf_hi(g7), acc.y);
    }
    for (; i < deg; ++i) {
        int2 c = s[i];
        float v = __int_as_float(c.y);
        unsigned g = xb[(size_t)c.x * 64 + lane];
        acc.x = fmaf(v, bf_lo(g), acc.x);
        acc.y = fmaf(v, bf_hi(g), acc.y);
    }
    outb[(size_t)row * 64 + lane] = pack_bf2(acc.x, acc.y);
}

// ---------------------------------------------------------------- SpMM layers 2-3

__global__ __launch_bounds__(256) void spmm2_kernel(
        const int* __restrict__ cnt, const int2* __restrict__ ell,
        const unsigned* __restrict__ xb,
        float* __restrict__ out32, unsigned* __restrict__ outb) {
    int wid = threadIdx.x >> 6, lane = threadIdx.x & 63;
    int rowA = blockIdx.x * 8 + wid * 2;
    int rowB = rowA + 1;
    int degA = min(cnt[rowA], ELL_CAP);
    int degB = min(cnt[rowB], ELL_CAP);
    const int2* baseA = ell + (size_t)rowA * ELL_CAP;
    const int2* baseB = ell + (size_t)rowB * ELL_CAP;
    unsigned swA = xb[(size_t)rowA * 64 + lane];
    unsigned swB = xb[(size_t)rowB * 64 + lane];
    float2 accA, accB;
    accA.x = ALPHA_F * bf_lo(swA); accA.y = ALPHA_F * bf_hi(swA);
    accB.x = ALPHA_F * bf_lo(swB); accB.y = ALPHA_F * bf_hi(swB);
    int dmax = max(degA, degB);
    for (int i = 0; i < dmax; i += 8) {
        int4 pa0 = *reinterpret_cast<const int4*>(baseA + i);
        int4 pa1 = *reinterpret_cast<const int4*>(baseA + i + 2);
        int4 pa2 = *reinterpret_cast<const int4*>(baseA + i + 4);
        int4 pa3 = *reinterpret_cast<const int4*>(baseA + i + 6);
        int4 pb0 = *reinterpret_cast<const int4*>(baseB + i);
        int4 pb1 = *reinterpret_cast<const int4*>(baseB + i + 2);
        int4 pb2 = *reinterpret_cast<const int4*>(baseB + i + 4);
        int4 pb3 = *reinterpret_cast<const int4*>(baseB + i + 6);
        int ca0 = (i+0<degA)?pa0.x:0; float va0 = (i+0<degA)?__int_as_float(pa0.y):0.f;
        int ca1 = (i+1<degA)?pa0.z:0; float va1 = (i+1<degA)?__int_as_float(pa0.w):0.f;
        int ca2 = (i+2<degA)?pa1.x:0; float va2 = (i+2<degA)?__int_as_float(pa1.y):0.f;
        int ca3 = (i+3<degA)?pa1.z:0; float va3 = (i+3<degA)?__int_as_float(pa1.w):0.f;
        int ca4 = (i+4<degA)?pa2.x:0; float va4 = (i+4<degA)?__int_as_float(pa2.y):0.f;
        int ca5 = (i+5<degA)?pa2.z:0; float va5 = (i+5<degA)?__int_as_float(pa2.w):0.f;
        int ca6 = (i+6<degA)?pa3.x:0; float va6 = (i+6<degA)?__int_as_float(pa3.y):0.f;
        int ca7 = (i+7<degA)?pa3.z:0; float va7 = (i+7<degA)?__int_as_float(pa3.w):0.f;
        int cb0 = (i+0<degB)?pb0.x:0; float vb0 = (i+0<degB)?__int_as_float(pb0.y):0.f;
        int cb1 = (i+1<degB)?pb0.z:0; float vb1 = (i+1<degB)?__int_as_float(pb0.w):0.f;
        int cb2 = (i+2<degB)?pb1.x:0; float vb2 = (i+2<degB)?__int_as_float(pb1.y):0.f;
        int cb3 = (i+3<degB)?pb1.z:0; float vb3 = (i+3<degB)?__int_as_float(pb1.w):0.f;
        int cb4 = (i+4<degB)?pb2.x:0; float vb4 = (i+4<degB)?__int_as_float(pb2.y):0.f;
        int cb5 = (i+5<degB)?pb2.z:0; float vb5 = (i+5<degB)?__int_as_float(pb2.w):0.f;
        int cb6 = (i+6<degB)?pb3.x:0; float vb6 = (i+6<degB)?__int_as_float(pb3.y):0.f;
        int cb7 = (i+7<degB)?pb3.z:0; float vb7 = (i+7<degB)?__int_as_float(pb3.w):0.f;
        unsigned ga0 = xb[(size_t)ca0 * 64 + lane];
        unsigned ga1 = xb[(size_t)ca1 * 64 + lane];
        unsigned ga2 = xb[(size_t)ca2 * 64 + lane];
        unsigned ga3 = xb[(size_t)ca3 * 64 + lane];
        unsigned ga4 = xb[(size_t)ca4 * 64 + lane];
        unsigned ga5 = xb[(size_t)ca5 * 64 + lane];
        unsigned ga6 = xb[(size_t)ca6 * 64 + lane];
        unsigned ga7 = xb[(size_t)ca7 * 64 + lane];
        unsigned gb0 = xb[(size_t)cb0 * 64 + lane];
        unsigned gb1 = xb[(size_t)cb1 * 64 + lane];
        unsigned gb2 = xb[(size_t)cb2 * 64 + lane];
        unsigned gb3 = xb[(size_t)cb3 * 64 + lane];
        unsigned gb4 = xb[(size_t)cb4 * 64 + lane];
        unsigned gb5 = xb[(size_t)cb5 * 64 + lane];
        unsigned gb6 = xb[(size_t)cb6 * 64 + lane];
        unsigned gb7 = xb[(size_t)cb7 * 64 + lane];
        accA.x = fmaf(va0, bf_lo(ga0), accA.x); accA.y = fmaf(va0, bf_hi(ga0), accA.y);
        accA.x = fmaf(va1, bf_lo(ga1), accA.x); accA.y = fmaf(va1, bf_hi(ga1), accA.y);
        accA.x = fmaf(va2, bf_lo(ga2), accA.x); accA.y = fmaf(va2, bf_hi(ga2), accA.y);
        accA.x = fmaf(va3, bf_lo(ga3), accA.x); accA.y = fmaf(va3, bf_hi(ga3), accA.y);
        accA.x = fmaf(va4, bf_lo(ga4), accA.x); accA.y = fmaf(va4, bf_hi(ga4), accA.y);
        accA.x = fmaf(va5, bf_lo(ga5), accA.x); accA.y = fmaf(va5, bf_hi(ga5), accA.y);
        accA.x = fmaf(va6, bf_lo(ga6), accA.x); accA.y = fmaf(va6, bf_hi(ga6), accA.y);
        accA.x = fmaf(va7, bf_lo(ga7), accA.x); accA.y = fmaf(va7, bf_hi(ga7), accA.y);
        accB.x = fmaf(vb0, bf_lo(gb0), accB.x); accB.y = fmaf(vb0, bf_hi(gb0), accB.y);
        accB.x = fmaf(vb1, bf_lo(gb1), accB.x); accB.y = fmaf(vb1, bf_hi(gb1), accB.y);
        accB.x = fmaf(vb2, bf_lo(gb2), accB.x); accB.y = fmaf(vb2, bf_hi(gb2), accB.y);
        accB.x = fmaf(vb3, bf_lo(gb3), accB.x); accB.y = fmaf(vb3, bf_hi(gb3), accB.y);
        accB.x = fmaf(vb4, bf_lo(gb4), accB.x); accB.y = fmaf(vb4, bf_hi(gb4), accB.y);
        accB.x = fmaf(vb5, bf_lo(gb5), accB.x); accB.y = fmaf(vb5, bf_hi(gb5), accB.y);
        accB.x = fmaf(vb6, bf_lo(gb6), accB.x); accB.y = fmaf(vb6, bf_hi(gb6), accB.y);
        accB.x = fmaf(vb7, bf_lo(gb7), accB.x); accB.y = fmaf(vb7, bf_hi(gb7), accB.y);
    }
    if (out32) {
        out32[(size_t)rowA * 128 + lane] = accA.x;
        out32[(size_t)rowA * 128 + 64 + lane] = accA.y;
        out32[(size_t)rowB * 128 + lane] = accB.x;
        out32[(size_t)rowB * 128 + 64 + lane] = accB.y;
    }
    if (outb) {
        outb[(size_t)rowA * 64 + lane] = pack_bf2(accA.x, accA.y);
        outb[(size_t)rowB * 64 + lane] = pack_bf2(accB.x, accB.y);
    }
}

// ---------------------------------------------------------------- launch

extern "C" void kernel_launch(void* const* d_in, const int* in_sizes, int n_in,
                              void* d_out, int out_size, void* d_ws, size_t ws_size,
                              hipStream_t stream) {
    const float* image_feats = (const float*)d_in[0];
    const float* text_feats  = (const float*)d_in[1];
    const float* image_pref  = (const float*)d_in[2];
    const float* text_pref   = (const float*)d_in[3];
    const float* W_img       = (const float*)d_in[4];
    const float* b_img       = (const float*)d_in[5];
    const float* W_txt       = (const float*)d_in[6];
    const float* b_txt       = (const float*)d_in[7];
    const float* adj_vals    = (const float*)d_in[8];
    const int*   adj_rows    = (const int*)d_in[9];
    const int*   adj_cols    = (const int*)d_in[10];

    float* out = (float*)d_out;                          // [150000*128]

    char* ws = (char*)d_ws;
    size_t off = 0;
    auto alloc = [&](size_t bytes) { char* p = ws + off; off += (bytes + 255) & ~size_t(255); return p; };
    int*      cnt   = (int*)     alloc(N_TOTAL * sizeof(int));
    int2*     ell   = (int2*)    alloc((size_t)N_TOTAL * ELL_CAP * sizeof(int2));
    unsigned* m0    = (unsigned*)alloc((size_t)N_TOTAL * 64 * sizeof(unsigned));
    unsigned* m1    = (unsigned*)alloc((size_t)N_TOTAL * 64 * sizeof(unsigned));
    char*     WtiT  = (char*)    alloc((size_t)NC_IMG * 16384);
    char*     WttT  = (char*)    alloc((size_t)3 * 16384);
    char*     At    = (char*)    alloc((size_t)G_GEMM * 35 * 4096);   // 448 MB
    (void)ws_size; (void)out_size; (void)n_in; (void)in_sizes;

    // --- prep: zero cnt + tiled/swizzled bf16 B ---
    prep_kernel<<<512, 256, 0, stream>>>(W_img, W_txt, cnt, WtiT, WttT);

    // --- xpose: scatter || copy || sequential A -> packed bf16 At ---
    xpose_kernel<<<X_SCAT + X_COPY + X_TIMG + X_TTXT, 256, 0, stream>>>(
        image_feats, text_feats, At, adj_rows, adj_cols, adj_vals, cnt, ell,
        image_pref, text_pref, m0);

    // --- GEMM from packed At (all staging linear, pure-LDS compute) ---
    unsigned* m0_items = m0 + (size_t)N_USERS * 64;
    gemm_kernel<<<G_GEMM, 256, 0, stream>>>(At, WtiT, WttT, b_img, b_txt, m0_items);

    // --- layer 1 (+ canonical in-kernel sort), then layers 2-3 ---
    const int ROW_GRID4 = (N_TOTAL + 3) / 4;
    const int ROW_GRID8 = N_TOTAL / 8;
    spmm_sort_kernel<<<ROW_GRID4, 256, 0, stream>>>(cnt, ell, m0, m1);
    spmm2_kernel<<<ROW_GRID8, 256, 0, stream>>>(cnt, ell, m1, nullptr, m0);
    spmm2_kernel<<<ROW_GRID8, 256, 0, stream>>>(cnt, ell, m0, out, nullptr);
}

// Round 18
// 963.813 us; speedup vs baseline: 1.2363x; 1.2363x over previous
//
#include <hip/hip_runtime.h>
#include <hip/hip_bf16.h>

#define N_USERS 100000
#define N_ITEMS 50000
#define N_TOTAL 150000
#define NNZ     4000000
#define ALPHA_F 0.8f
#define ELL_CAP 128

#define G_SCAT 1024
#define G_COPY 128
#define G_PRE  (G_SCAT + G_COPY)
#define G_GEMM 3125           // N_ITEMS / 16 exactly
#define NC_IMG 64             // img chunks of K=64
#define NC_ALL 70             // + 6 txt chunks of K=64

typedef __attribute__((ext_vector_type(8))) short bf16x8;
typedef __attribute__((ext_vector_type(4))) float f32x4;

static __device__ __forceinline__ short f2bf(float f) {
    unsigned u = __builtin_bit_cast(unsigned, f);
    unsigned r = (u + 0x7fff + ((u >> 16) & 1)) >> 16;   // RTNE
    return (short)r;
}
static __device__ __forceinline__ unsigned pack_bf2(float a, float b) {
    return (unsigned)(unsigned short)f2bf(a) | ((unsigned)(unsigned short)f2bf(b) << 16);
}
static __device__ __forceinline__ float bf_lo(unsigned u) { return __uint_as_float(u << 16); }
static __device__ __forceinline__ float bf_hi(unsigned u) { return __uint_as_float(u & 0xFFFF0000u); }

static __device__ __forceinline__ void gload_lds16(const void* src, void* dst) {
    __builtin_amdgcn_global_load_lds(
        (const __attribute__((address_space(1))) unsigned*)src,
        (__attribute__((address_space(3))) unsigned*)dst, 16, 0, 0);
}

// ---------------------------------------------------------------- prep

__global__ __launch_bounds__(256) void prep_kernel(const float* __restrict__ Wimg,
                                                   const float* __restrict__ Wtxt,
                                                   int* __restrict__ cnt,
                                                   char* __restrict__ WtiT,
                                                   char* __restrict__ WttT) {
    const int T0 = N_TOTAL;
    const int T1 = T0 + 4096 * 64;
    const int T2 = T1 + 384 * 64;
    int i = blockIdx.x * 256 + threadIdx.x;
    int stride = gridDim.x * 256;
    for (; i < T2; i += stride) {
        if (i < T0) {
            cnt[i] = 0;
        } else if (i < T1) {
            int idx = i - T0; int k = idx >> 6, n = idx & 63;
            int c = k >> 6, kk = k & 63;
            *(short*)(WtiT + c * 8192 + n * 128 + ((kk * 2) ^ ((n & 7) << 4)))
                = f2bf(Wimg[(size_t)k * 64 + n]);
        } else {
            int idx = i - T1; int k = idx >> 6, n = idx & 63;
            int c = k >> 6, kk = k & 63;
            *(short*)(WttT + c * 8192 + n * 128 + ((kk * 2) ^ ((n & 7) << 4)))
                = f2bf(Wtxt[(size_t)k * 64 + n]);
        }
    }
}

// ---------------------------------------------------------------- mega kernel
// [0, G_SCAT):      ELL scatter
// [G_SCAT, G_PRE):  user pref -> bf16 mirror
// [G_PRE, ...):     item GEMM, 16 rows/block, K-chunk 64, 6 blocks/CU.
// NEW: per-block chunk-order rotation (blk % 70) decorrelates address bits
// 8-13 across concurrent blocks -> spreads HBM channel load. Accumulation
// order rotated per-block (deterministic; fp reassociation noise only).

__global__ __launch_bounds__(256, 6) void mega_kernel(
        const float* __restrict__ Aimg, const float* __restrict__ Atxt,
        const char* __restrict__ WtiT, const char* __restrict__ WttT,
        const float* __restrict__ bimg, const float* __restrict__ btxt,
        unsigned* __restrict__ egob,
        const int* __restrict__ rows, const int* __restrict__ cols,
        const float* __restrict__ vals, int* __restrict__ cnt, int2* __restrict__ ell,
        const float* __restrict__ img_pref, const float* __restrict__ txt_pref) {
    __shared__ __align__(16) char abuf[2][4096];
    __shared__ __align__(16) char bbuf[2][8192];
    int b = blockIdx.x;
    int t = threadIdx.x;
    int wave = t >> 6, lane = t & 63;

    if (b < G_SCAT) {
        int i = b * 256 + t;
        int stride = G_SCAT * 256;
        for (; i < NNZ; i += stride) {
            int r = rows[i];
            int p = atomicAdd(&cnt[r], 1);
            if (p < ELL_CAP)
                ell[(size_t)r * ELL_CAP + p] = make_int2(cols[i], __float_as_int(vals[i]));
        }
        return;
    }
    if (b < G_PRE) {
        int idx = (b - G_SCAT) * 256 + t;
        int stride = G_COPY * 256;
        for (; idx < N_USERS * 16; idx += stride) {
            int row = idx >> 4, w4 = (idx & 15) << 2;
            float4 iv = *reinterpret_cast<const float4*>(&img_pref[(size_t)row * 64 + w4]);
            float4 tv = *reinterpret_cast<const float4*>(&txt_pref[(size_t)row * 64 + w4]);
            uint4 m;
            m.x = pack_bf2(iv.x, tv.x); m.y = pack_bf2(iv.y, tv.y);
            m.z = pack_bf2(iv.z, tv.z); m.w = pack_bf2(iv.w, tv.w);
            *reinterpret_cast<uint4*>(&egob[(size_t)row * 64 + w4]) = m;
        }
        return;
    }

    const int blk = b - G_PRE;
    const int row0 = blk * 16;
    const int col = lane & 15, kb = lane >> 4;
    const int rot = blk % NC_ALL;

    auto phys = [&](int ci) { int p = ci + rot; return p >= NC_ALL ? p - NC_ALL : p; };

    auto stage = [&](int pc, int bi) {
        const float* A; size_t rowbytes; const char* BT; int cc;
        if (pc < NC_IMG) { A = Aimg; rowbytes = 16384; BT = WtiT; cc = pc; }
        else             { A = Atxt; rowbytes = 1536;  BT = WttT; cc = pc - NC_IMG; }
        {
            int r = wave * 4 + (lane >> 4);
            int so = ((lane & 15) * 16) ^ ((r & 7) << 4);
            const char* src = (const char*)A + (size_t)(row0 + r) * rowbytes + cc * 256 + so;
            char* dst = abuf[bi] + wave * 1024 + lane * 16;
            gload_lds16(src, dst);
        }
        #pragma unroll
        for (int q = 0; q < 2; ++q) {
            int off = (q * 4 + wave) * 1024 + lane * 16;
            gload_lds16(BT + (size_t)cc * 8192 + off, bbuf[bi] + off);
        }
    };

    auto comp = [&](int bi, f32x4& acc) {
        const int r = col;
        const int aswz = (r & 7) << 4;
        const char* ab = abuf[bi] + r * 256;
        const int n = 16 * wave + col;
        const char* bb = bbuf[bi] + n * 128;
        const int bswz = (n & 7) << 4;
        #pragma unroll
        for (int ks = 0; ks < 2; ++ks) {
            int la = ks * 128 + kb * 32;
            float4 a0 = *(const float4*)(ab + (la ^ aswz));
            float4 a1 = *(const float4*)(ab + ((la + 16) ^ aswz));
            bf16x8 af;
            af[0]=f2bf(a0.x); af[1]=f2bf(a0.y); af[2]=f2bf(a0.z); af[3]=f2bf(a0.w);
            af[4]=f2bf(a1.x); af[5]=f2bf(a1.y); af[6]=f2bf(a1.z); af[7]=f2bf(a1.w);
            bf16x8 bf = *(const bf16x8*)(bb + ((ks * 64 + kb * 16) ^ bswz));
            acc = __builtin_amdgcn_mfma_f32_16x16x32_bf16(af, bf, acc, 0, 0, 0);
        }
    };

    f32x4 ai = {0.f,0.f,0.f,0.f}, at4 = {0.f,0.f,0.f,0.f};

    stage(phys(0), 0);
    for (int ci = 0; ci < NC_ALL; ++ci) {
        int bi = ci & 1;
        int pc = phys(ci);
        if (ci + 1 < NC_ALL) {
            stage(phys(ci + 1), bi ^ 1);
            asm volatile("s_waitcnt vmcnt(3)" ::: "memory");
        } else {
            asm volatile("s_waitcnt vmcnt(0)" ::: "memory");
        }
        __builtin_amdgcn_s_barrier();
        __builtin_amdgcn_sched_barrier(0);
        if (pc < NC_IMG) comp(bi, ai);
        else             comp(bi, at4);
        __builtin_amdgcn_sched_barrier(0);
        __builtin_amdgcn_s_barrier();
    }

    float bv_i = bimg[16 * wave + col];
    float bv_t = btxt[16 * wave + col];
    float ssi[4], sst[4];
    #pragma unroll
    for (int i = 0; i < 4; ++i) {
        ai[i] += bv_i; at4[i] += bv_t;
        ssi[i] = ai[i] * ai[i];
        sst[i] = at4[i] * at4[i];
    }
    #pragma unroll
    for (int off = 1; off < 16; off <<= 1) {
        #pragma unroll
        for (int i = 0; i < 4; ++i) {
            ssi[i] += __shfl_xor(ssi[i], off, 64);
            sst[i] += __shfl_xor(sst[i], off, 64);
        }
    }
    float* S = (float*)abuf;
    __syncthreads();
    if (col == 0) {
        #pragma unroll
        for (int i = 0; i < 4; ++i) {
            S[wave * 16 + kb * 4 + i]      = ssi[i];
            S[64 + wave * 16 + kb * 4 + i] = sst[i];
        }
    }
    __syncthreads();
    unsigned* egob_items = egob + (size_t)N_USERS * 64;
    #pragma unroll
    for (int i = 0; i < 4; ++i) {
        int r = kb * 4 + i;
        float ti = S[r] + S[16 + r] + S[32 + r] + S[48 + r];
        float tt = S[64 + r] + S[80 + r] + S[96 + r] + S[112 + r];
        float rni = 1.0f / fmaxf(sqrtf(ti), 1e-12f);
        float rnt = 1.0f / fmaxf(sqrtf(tt), 1e-12f);
        egob_items[(size_t)(row0 + r) * 64 + 16 * wave + col] =
            pack_bf2(ai[i] * rni, at4[i] * rnt);
    }
}

// ---------------------------------------------------------------- SpMM layer 1 + fused sort

__global__ __launch_bounds__(256) void spmm_sort_kernel(
        const int* __restrict__ cnt, int2* __restrict__ ell,
        const unsigned* __restrict__ xb, unsigned* __restrict__ outb) {
    __shared__ __align__(16) int2 srt[4][ELL_CAP];
    int wid = threadIdx.x >> 6, lane = threadIdx.x & 63;
    int row = blockIdx.x * 4 + wid;
    bool valid = row < N_TOTAL;
    int deg = 0;
    int2* base = nullptr;
    int2 e0 = make_int2(0x7FFFFFFF, 0), e1 = e0;
    if (valid) {
        deg = min(cnt[row], ELL_CAP);
        base = ell + (size_t)row * ELL_CAP;
        if (lane < deg)      e0 = base[lane];
        if (lane + 64 < deg) e1 = base[lane + 64];
    }
    #pragma unroll
    for (int k = 2; k <= 128; k <<= 1) {
        #pragma unroll
        for (int j = 64; j >= 1; j >>= 1) {
            if (j >= k) continue;
            if (j == 64) {
                if (e0.x > e1.x) { int2 tmp = e0; e0 = e1; e1 = tmp; }
            } else {
                int2 p0, p1;
                p0.x = __shfl_xor(e0.x, j, 64); p0.y = __shfl_xor(e0.y, j, 64);
                p1.x = __shfl_xor(e1.x, j, 64); p1.y = __shfl_xor(e1.y, j, 64);
                bool up0 = ((lane & k) == 0);
                bool up1 = (((lane + 64) & k) == 0);
                bool lo0 = ((lane & j) == 0);
                bool keepmin0 = (up0 == lo0);
                bool keepmin1 = (up1 == lo0);
                if (keepmin0 ? (e0.x > p0.x) : (e0.x < p0.x)) e0 = p0;
                if (keepmin1 ? (e1.x > p1.x) : (e1.x < p1.x)) e1 = p1;
            }
        }
    }
    if (valid) {
        if (lane < deg)      base[lane]      = e0;
        if (lane + 64 < deg) base[lane + 64] = e1;
    }
    srt[wid][lane] = e0;
    srt[wid][lane + 64] = e1;
    __syncthreads();
    if (!valid) return;
    unsigned sw = xb[(size_t)row * 64 + lane];
    float2 acc;
    acc.x = ALPHA_F * bf_lo(sw);
    acc.y = ALPHA_F * bf_hi(sw);
    const int2* s = srt[wid];
    int i = 0;
    for (; i + 8 <= deg; i += 8) {
        int4 p0 = *reinterpret_cast<const int4*>(s + i);
        int4 p1 = *reinterpret_cast<const int4*>(s + i + 2);
        int4 p2 = *reinterpret_cast<const int4*>(s + i + 4);
        int4 p3 = *reinterpret_cast<const int4*>(s + i + 6);
        unsigned g0 = xb[(size_t)p0.x * 64 + lane];
        unsigned g1 = xb[(size_t)p0.z * 64 + lane];
        unsigned g2 = xb[(size_t)p1.x * 64 + lane];
        unsigned g3 = xb[(size_t)p1.z * 64 + lane];
        unsigned g4 = xb[(size_t)p2.x * 64 + lane];
        unsigned g5 = xb[(size_t)p2.z * 64 + lane];
        unsigned g6 = xb[(size_t)p3.x * 64 + lane];
        unsigned g7 = xb[(size_t)p3.z * 64 + lane];
        float v0 = __int_as_float(p0.y), v1 = __int_as_float(p0.w);
        float v2 = __int_as_float(p1.y), v3 = __int_as_float(p1.w);
        float v4 = __int_as_float(p2.y), v5 = __int_as_float(p2.w);
        float v6 = __int_as_float(p3.y), v7 = __int_as_float(p3.w);
        acc.x = fmaf(v0, bf_lo(g0), acc.x); acc.y = fmaf(v0, bf_hi(g0), acc.y);
        acc.x = fmaf(v1, bf_lo(g1), acc.x); acc.y = fmaf(v1, bf_hi(g1), acc.y);
        acc.x = fmaf(v2, bf_lo(g2), acc.x); acc.y = fmaf(v2, bf_hi(g2), acc.y);
        acc.x = fmaf(v3, bf_lo(g3), acc.x); acc.y = fmaf(v3, bf_hi(g3), acc.y);
        acc.x = fmaf(v4, bf_lo(g4), acc.x); acc.y = fmaf(v4, bf_hi(g4), acc.y);
        acc.x = fmaf(v5, bf_lo(g5), acc.x); acc.y = fmaf(v5, bf_hi(g5), acc.y);
        acc.x = fmaf(v6, bf_lo(g6), acc.x); acc.y = fmaf(v6, bf_hi(g6), acc.y);
        acc.x = fmaf(v7, bf_lo(g7), acc.x); acc.y = fmaf(v7, bf_hi(g7), acc.y);
    }
    for (; i < deg; ++i) {
        int2 c = s[i];
        float v = __int_as_float(c.y);
        unsigned g = xb[(size_t)c.x * 64 + lane];
        acc.x = fmaf(v, bf_lo(g), acc.x);
        acc.y = fmaf(v, bf_hi(g), acc.y);
    }
    outb[(size_t)row * 64 + lane] = pack_bf2(acc.x, acc.y);
}

// ---------------------------------------------------------------- SpMM layers 2-3

__global__ __launch_bounds__(256) void spmm2_kernel(
        const int* __restrict__ cnt, const int2* __restrict__ ell,
        const unsigned* __restrict__ xb,
        float* __restrict__ out32, unsigned* __restrict__ outb) {
    int wid = threadIdx.x >> 6, lane = threadIdx.x & 63;
    int rowA = blockIdx.x * 8 + wid * 2;
    int rowB = rowA + 1;
    int degA = min(cnt[rowA], ELL_CAP);
    int degB = min(cnt[rowB], ELL_CAP);
    const int2* baseA = ell + (size_t)rowA * ELL_CAP;
    const int2* baseB = ell + (size_t)rowB * ELL_CAP;
    unsigned swA = xb[(size_t)rowA * 64 + lane];
    unsigned swB = xb[(size_t)rowB * 64 + lane];
    float2 accA, accB;
    accA.x = ALPHA_F * bf_lo(swA); accA.y = ALPHA_F * bf_hi(swA);
    accB.x = ALPHA_F * bf_lo(swB); accB.y = ALPHA_F * bf_hi(swB);
    int dmax = max(degA, degB);
    for (int i = 0; i < dmax; i += 8) {
        int4 pa0 = *reinterpret_cast<const int4*>(baseA + i);
        int4 pa1 = *reinterpret_cast<const int4*>(baseA + i + 2);
        int4 pa2 = *reinterpret_cast<const int4*>(baseA + i + 4);
        int4 pa3 = *reinterpret_cast<const int4*>(baseA + i + 6);
        int4 pb0 = *reinterpret_cast<const int4*>(baseB + i);
        int4 pb1 = *reinterpret_cast<const int4*>(baseB + i + 2);
        int4 pb2 = *reinterpret_cast<const int4*>(baseB + i + 4);
        int4 pb3 = *reinterpret_cast<const int4*>(baseB + i + 6);
        int ca0 = (i+0<degA)?pa0.x:0; float va0 = (i+0<degA)?__int_as_float(pa0.y):0.f;
        int ca1 = (i+1<degA)?pa0.z:0; float va1 = (i+1<degA)?__int_as_float(pa0.w):0.f;
        int ca2 = (i+2<degA)?pa1.x:0; float va2 = (i+2<degA)?__int_as_float(pa1.y):0.f;
        int ca3 = (i+3<degA)?pa1.z:0; float va3 = (i+3<degA)?__int_as_float(pa1.w):0.f;
        int ca4 = (i+4<degA)?pa2.x:0; float va4 = (i+4<degA)?__int_as_float(pa2.y):0.f;
        int ca5 = (i+5<degA)?pa2.z:0; float va5 = (i+5<degA)?__int_as_float(pa2.w):0.f;
        int ca6 = (i+6<degA)?pa3.x:0; float va6 = (i+6<degA)?__int_as_float(pa3.y):0.f;
        int ca7 = (i+7<degA)?pa3.z:0; float va7 = (i+7<degA)?__int_as_float(pa3.w):0.f;
        int cb0 = (i+0<degB)?pb0.x:0; float vb0 = (i+0<degB)?__int_as_float(pb0.y):0.f;
        int cb1 = (i+1<degB)?pb0.z:0; float vb1 = (i+1<degB)?__int_as_float(pb0.w):0.f;
        int cb2 = (i+2<degB)?pb1.x:0; float vb2 = (i+2<degB)?__int_as_float(pb1.y):0.f;
        int cb3 = (i+3<degB)?pb1.z:0; float vb3 = (i+3<degB)?__int_as_float(pb1.w):0.f;
        int cb4 = (i+4<degB)?pb2.x:0; float vb4 = (i+4<degB)?__int_as_float(pb2.y):0.f;
        int cb5 = (i+5<degB)?pb2.z:0; float vb5 = (i+5<degB)?__int_as_float(pb2.w):0.f;
        int cb6 = (i+6<degB)?pb3.x:0; float vb6 = (i+6<degB)?__int_as_float(pb3.y):0.f;
        int cb7 = (i+7<degB)?pb3.z:0; float vb7 = (i+7<degB)?__int_as_float(pb3.w):0.f;
        unsigned ga0 = xb[(size_t)ca0 * 64 + lane];
        unsigned ga1 = xb[(size_t)ca1 * 64 + lane];
        unsigned ga2 = xb[(size_t)ca2 * 64 + lane];
        unsigned ga3 = xb[(size_t)ca3 * 64 + lane];
        unsigned ga4 = xb[(size_t)ca4 * 64 + lane];
        unsigned ga5 = xb[(size_t)ca5 * 64 + lane];
        unsigned ga6 = xb[(size_t)ca6 * 64 + lane];
        unsigned ga7 = xb[(size_t)ca7 * 64 + lane];
        unsigned gb0 = xb[(size_t)cb0 * 64 + lane];
        unsigned gb1 = xb[(size_t)cb1 * 64 + lane];
        unsigned gb2 = xb[(size_t)cb2 * 64 + lane];
        unsigned gb3 = xb[(size_t)cb3 * 64 + lane];
        unsigned gb4 = xb[(size_t)cb4 * 64 + lane];
        unsigned gb5 = xb[(size_t)cb5 * 64 + lane];
        unsigned gb6 = xb[(size_t)cb6 * 64 + lane];
        unsigned gb7 = xb[(size_t)cb7 * 64 + lane];
        accA.x = fmaf(va0, bf_lo(ga0), accA.x); accA.y = fmaf(va0, bf_hi(ga0), accA.y);
        accA.x = fmaf(va1, bf_lo(ga1), accA.x); accA.y = fmaf(va1, bf_hi(ga1), accA.y);
        accA.x = fmaf(va2, bf_lo(ga2), accA.x); accA.y = fmaf(va2, bf_hi(ga2), accA.y);
        accA.x = fmaf(va3, bf_lo(ga3), accA.x); accA.y = fmaf(va3, bf_hi(ga3), accA.y);
        accA.x = fmaf(va4, bf_lo(ga4), accA.x); accA.y = fmaf(va4, bf_hi(ga4), accA.y);
        accA.x = fmaf(va5, bf_lo(ga5), accA.x); accA.y = fmaf(va5, bf_hi(ga5), accA.y);
        accA.x = fmaf(va6, bf_lo(ga6), accA.x); accA.y = fmaf(va6, bf_hi(ga6), accA.y);
        accA.x = fmaf(va7, bf_lo(ga7), accA.x); accA.y = fmaf(va7, bf_hi(ga7), accA.y);
        accB.x = fmaf(vb0, bf_lo(gb0), accB.x); accB.y = fmaf(vb0, bf_hi(gb0), accB.y);
        accB.x = fmaf(vb1, bf_lo(gb1), accB.x); accB.y = fmaf(vb1, bf_hi(gb1), accB.y);
        accB.x = fmaf(vb2, bf_lo(gb2), accB.x); accB.y = fmaf(vb2, bf_hi(gb2), accB.y);
        accB.x = fmaf(vb3, bf_lo(gb3), accB.x); accB.y = fmaf(vb3, bf_hi(gb3), accB.y);
        accB.x = fmaf(vb4, bf_lo(gb4), accB.x); accB.y = fmaf(vb4, bf_hi(gb4), accB.y);
        accB.x = fmaf(vb5, bf_lo(gb5), accB.x); accB.y = fmaf(vb5, bf_hi(gb5), accB.y);
        accB.x = fmaf(vb6, bf_lo(gb6), accB.x); accB.y = fmaf(vb6, bf_hi(gb6), accB.y);
        accB.x = fmaf(vb7, bf_lo(gb7), accB.x); accB.y = fmaf(vb7, bf_hi(gb7), accB.y);
    }
    if (out32) {
        out32[(size_t)rowA * 128 + lane] = accA.x;
        out32[(size_t)rowA * 128 + 64 + lane] = accA.y;
        out32[(size_t)rowB * 128 + lane] = accB.x;
        out32[(size_t)rowB * 128 + 64 + lane] = accB.y;
    }
    if (outb) {
        outb[(size_t)rowA * 64 + lane] = pack_bf2(accA.x, accA.y);
        outb[(size_t)rowB * 64 + lane] = pack_bf2(accB.x, accB.y);
    }
}

// ---------------------------------------------------------------- launch

extern "C" void kernel_launch(void* const* d_in, const int* in_sizes, int n_in,
                              void* d_out, int out_size, void* d_ws, size_t ws_size,
                              hipStream_t stream) {
    const float* image_feats = (const float*)d_in[0];
    const float* text_feats  = (const float*)d_in[1];
    const float* image_pref  = (const float*)d_in[2];
    const float* text_pref   = (const float*)d_in[3];
    const float* W_img       = (const float*)d_in[4];
    const float* b_img       = (const float*)d_in[5];
    const float* W_txt       = (const float*)d_in[6];
    const float* b_txt       = (const float*)d_in[7];
    const float* adj_vals    = (const float*)d_in[8];
    const int*   adj_rows    = (const int*)d_in[9];
    const int*   adj_cols    = (const int*)d_in[10];

    float* out = (float*)d_out;                          // [150000*128]

    char* ws = (char*)d_ws;
    size_t off = 0;
    auto alloc = [&](size_t bytes) { char* p = ws + off; off += (bytes + 255) & ~size_t(255); return p; };
    int*      cnt   = (int*)     alloc(N_TOTAL * sizeof(int));
    int2*     ell   = (int2*)    alloc((size_t)N_TOTAL * ELL_CAP * sizeof(int2));
    unsigned* m0    = (unsigned*)alloc((size_t)N_TOTAL * 64 * sizeof(unsigned));
    unsigned* m1    = (unsigned*)alloc((size_t)N_TOTAL * 64 * sizeof(unsigned));
    char*     WtiT  = (char*)    alloc((size_t)NC_IMG * 8192);
    char*     WttT  = (char*)    alloc((size_t)6 * 8192);
    (void)ws_size; (void)out_size; (void)n_in; (void)in_sizes;

    // --- prep: zero cnt + tiled/swizzled bf16 B ---
    prep_kernel<<<512, 256, 0, stream>>>(W_img, W_txt, cnt, WtiT, WttT);

    // --- mega: scatter || copy || GEMM (chunk-rotated A stream) ---
    mega_kernel<<<G_PRE + G_GEMM, 256, 0, stream>>>(
        image_feats, text_feats, WtiT, WttT, b_img, b_txt, m0,
        adj_rows, adj_cols, adj_vals, cnt, ell, image_pref, text_pref);

    // --- layer 1 (+ canonical in-kernel sort), then layers 2-3 ---
    const int ROW_GRID4 = (N_TOTAL + 3) / 4;
    const int ROW_GRID8 = N_TOTAL / 8;
    spmm_sort_kernel<<<ROW_GRID4, 256, 0, stream>>>(cnt, ell, m0, m1);
    spmm2_kernel<<<ROW_GRID8, 256, 0, stream>>>(cnt, ell, m1, nullptr, m0);
    spmm2_kernel<<<ROW_GRID8, 256, 0, stream>>>(cnt, ell, m0, out, nullptr);
}